// Round 3
// baseline (2921.972 us; speedup 1.0000x reference)
//
#include <hip/hip_runtime.h>

#define M_MAPS 4096
#define F_DIM  256
#define NPOOL  256
#define RM     4          // correlation rows per block
#define THREADS 512
#define EPT    8          // sort elements per thread = M_MAPS/THREADS

// branchless compare-exchange; desc==true keeps the larger value in `a`.
__device__ __forceinline__ void ce(float& a, float& b, bool desc) {
    float lo = fminf(a, b), hi = fmaxf(a, b);
    a = desc ? hi : lo;
    b = desc ? lo : hi;
}

// bitonic stage with element-distance j = d*8 (d = lane distance 1..32),
// executed as a wave-internal shuffle butterfly on this thread's 8 elements.
__device__ __forceinline__ void lane_stage(float (&v)[EPT], int tid, int d, int k) {
    // lower-index side iff (tid & d)==0; desc iff (globalIdx & k)==0 (uniform
    // over the thread's 8 elements since k >= 16).
    const bool keepmax = (((tid & d) == 0) == (((tid * EPT) & k) == 0));
    #pragma unroll
    for (int e = 0; e < EPT; ++e) {
        float w = __shfl_xor(v[e], d, 64);
        v[e] = keepmax ? fmaxf(v[e], w) : fminf(v[e], w);
    }
}

// final intra-thread merge stages j = 4,2,1 (direction uniform per thread)
__device__ __forceinline__ void intra_tail(float (&v)[EPT], bool desc) {
    #pragma unroll
    for (int j = 4; j > 0; j >>= 1)
        #pragma unroll
        for (int e = 0; e < EPT; ++e) {
            int f = e ^ j;
            if (f > e) ce(v[e], v[f], desc);
        }
}

__global__ __launch_bounds__(THREADS, 4)
void corr_sort_pool_kernel(const float* __restrict__ x, float* __restrict__ out) {
    __shared__ float rows[RM][M_MAPS];   // 64 KB: RM correlation rows

    const int tid = threadIdx.x;
    const int g   = blockIdx.x;
    // XCD-aware mapping: 2 XCDs per batch so each 4 MB panel stays L2-local.
    const int b   = (g & 7) >> 1;                 // batch 0..3
    const int gi  = ((g >> 3) << 1) | (g & 1);    // 0..1023 within batch
    const int m0  = gi * RM;
    const float* __restrict__ xb = x + (size_t)b * (M_MAPS * F_DIM);

    // ---- phase A: RM correlation rows; accumulators in registers ----
    float acc[RM][EPT];
    #pragma unroll
    for (int r = 0; r < RM; ++r)
        #pragma unroll
        for (int nn = 0; nn < EPT; ++nn) acc[r][nn] = 0.0f;

    for (int c = 0; c < F_DIM / 8; ++c) {         // 32 f-chunks of 8 floats
        float4 u[RM][2];                          // own rows: wave-uniform loads
        #pragma unroll
        for (int r = 0; r < RM; ++r) {
            const float4* pu = (const float4*)(xb + (size_t)(m0 + r) * F_DIM) + c * 2;
            u[r][0] = pu[0];
            u[r][1] = pu[1];
        }
        #pragma unroll
        for (int nn = 0; nn < EPT; ++nn) {
            const int n = tid + nn * THREADS;
            const float4* pv = (const float4*)(xb + (size_t)n * F_DIM) + c * 2;
            float4 v0 = pv[0];
            float4 v1 = pv[1];
            #pragma unroll
            for (int r = 0; r < RM; ++r) {
                acc[r][nn] += v0.x*u[r][0].x + v0.y*u[r][0].y + v0.z*u[r][0].z + v0.w*u[r][0].w
                            + v1.x*u[r][1].x + v1.y*u[r][1].y + v1.z*u[r][1].z + v1.w*u[r][1].w;
            }
        }
    }
    #pragma unroll
    for (int r = 0; r < RM; ++r)
        #pragma unroll
        for (int nn = 0; nn < EPT; ++nn)
            rows[r][tid + nn * THREADS] = acc[r][nn] * (1.0f / F_DIM);
    __syncthreads();

    // ---- phase B: per row, descending bitonic sort, register-resident ----
    for (int r = 0; r < RM; ++r) {
        float* R = rows[r];

        // load this thread's contiguous 8 elements (indices tid*8 .. tid*8+7)
        float v[EPT];
        {
            float4 a0 = *(const float4*)&R[tid * EPT];
            float4 a1 = *(const float4*)&R[tid * EPT + 4];
            v[0]=a0.x; v[1]=a0.y; v[2]=a0.z; v[3]=a0.w;
            v[4]=a1.x; v[5]=a1.y; v[6]=a1.z; v[7]=a1.w;
        }

        // k = 2,4,8: fully intra-thread (direction varies inside the 8-block)
        #pragma unroll
        for (int k = 2; k <= EPT; k <<= 1)
            #pragma unroll
            for (int j = k >> 1; j > 0; j >>= 1)
                #pragma unroll
                for (int e = 0; e < EPT; ++e) {
                    int f = e ^ j;
                    if (f > e) ce(v[e], v[f], (((tid * EPT + e) & k) == 0));
                }

        // k = 16 .. 512: shuffle stages (j=k/2..8), then intra tail (j=4,2,1)
        #pragma unroll
        for (int k = 16; k <= 512; k <<= 1) {
            #pragma unroll
            for (int j = k >> 1; j >= EPT; j >>= 1)
                lane_stage(v, tid, j >> 3, k);
            intra_tail(v, ((tid * EPT) & k) == 0);
        }

        // k = 1024, 2048, 4096: LDS for j>=512, shuffles for j=256..8, tail
        #pragma unroll
        for (int k = 1024; k <= M_MAPS; k <<= 1) {
            // own-region write (disjoint per thread; no barrier needed before)
            *(float4*)&R[tid * EPT]     = make_float4(v[0], v[1], v[2], v[3]);
            *(float4*)&R[tid * EPT + 4] = make_float4(v[4], v[5], v[6], v[7]);
            __syncthreads();
            #pragma unroll
            for (int j = k >> 1; j >= 512; j >>= 1) {
                const int i0 = tid * 4;                         // 4 pairs/thread
                const int p  = ((i0 & ~(j - 1)) << 1) | (i0 & (j - 1));
                const bool desc = ((p & k) == 0);
                float4 A = *(float4*)&R[p];
                float4 B = *(float4*)&R[p + j];
                ce(A.x, B.x, desc); ce(A.y, B.y, desc);
                ce(A.z, B.z, desc); ce(A.w, B.w, desc);
                *(float4*)&R[p]     = A;
                *(float4*)&R[p + j] = B;
                __syncthreads();
            }
            {
                float4 a0 = *(const float4*)&R[tid * EPT];
                float4 a1 = *(const float4*)&R[tid * EPT + 4];
                v[0]=a0.x; v[1]=a0.y; v[2]=a0.z; v[3]=a0.w;
                v[4]=a1.x; v[5]=a1.y; v[6]=a1.z; v[7]=a1.w;
            }
            #pragma unroll
            for (int j = 256; j >= EPT; j >>= 1)
                lane_stage(v, tid, j >> 3, k);
            intra_tail(v, ((tid * EPT) & k) == 0);
        }

        // ---- phase C: emit percentile ranks straight from registers ----
        // ranks = round(linspace(1, 4095, 256)); step s = 4094/255 ≈ 16.055.
        // For sorted index idx, candidate pool slot i = round((idx-1)/s);
        // verify with the reference's own formula. No ties (margin >= 0.03
        // in i-space vs fp32 error ~1e-5), so roundf matches jnp.round.
        #pragma unroll
        for (int e = 0; e < EPT; ++e) {
            const int idx = tid * EPT + e;
            const int i = (int)roundf((float)(idx - 1) * (255.0f / 4094.0f));
            if (i >= 0 && i < NPOOL) {
                const int rk = (int)roundf(1.0f + (float)i * (4094.0f / 255.0f));
                if (rk == idx)
                    out[((size_t)(b * M_MAPS + m0 + r)) * NPOOL + i] = v[e];
            }
        }
        __syncthreads();   // rows[r] fully consumed before next row reuses LDS pipe
    }
}

extern "C" void kernel_launch(void* const* d_in, const int* in_sizes, int n_in,
                              void* d_out, int out_size, void* d_ws, size_t ws_size,
                              hipStream_t stream) {
    const float* x = (const float*)d_in[0];
    float* out = (float*)d_out;
    (void)in_sizes; (void)n_in; (void)out_size; (void)d_ws; (void)ws_size;
    corr_sort_pool_kernel<<<(4 * M_MAPS) / RM, THREADS, 0, stream>>>(x, out);
}

// Round 7
// 1284.001 us; speedup vs baseline: 2.2757x; 2.2757x over previous
//
#include <hip/hip_runtime.h>
#include <hip/hip_bf16.h>

#define M_MAPS 4096
#define F_DIM  256
#define NPOOL  256
#define NBATCH 4
#define BM     16          // correlation rows per block (one MFMA M-tile)
#define THREADS 512
#define EPT    8           // sort elements per thread
#define NT     32          // n-tiles per wave: 4096 / (8 waves * 16 cols)

typedef __attribute__((ext_vector_type(8))) short bf16x8;
typedef __attribute__((ext_vector_type(4))) float f32x4;

__device__ __forceinline__ unsigned short f2bf_bits(float f) {
    __hip_bfloat16 h = __float2bfloat16(f);
    return __builtin_bit_cast(unsigned short, h);
}
__device__ __forceinline__ float bf_bits2f(unsigned short s) {
    __hip_bfloat16 h = __builtin_bit_cast(__hip_bfloat16, s);
    return __bfloat162float(h);
}

// ---------- pre-kernel: split fp32 x into bf16 hi + bf16 lo ----------
__global__ __launch_bounds__(256)
void cvt_split_kernel(const float* __restrict__ x, unsigned short* __restrict__ hi,
                      unsigned short* __restrict__ lo) {
    const int n4 = NBATCH * M_MAPS * F_DIM / 4;
    for (int i = blockIdx.x * blockDim.x + threadIdx.x; i < n4;
         i += gridDim.x * blockDim.x) {
        float4 v = ((const float4*)x)[i];
        float f[4] = {v.x, v.y, v.z, v.w};
        unsigned short h[4], l[4];
        #pragma unroll
        for (int j = 0; j < 4; ++j) {
            h[j] = f2bf_bits(f[j]);
            l[j] = f2bf_bits(f[j] - bf_bits2f(h[j]));
        }
        ((ushort4*)hi)[i] = make_ushort4(h[0], h[1], h[2], h[3]);
        ((ushort4*)lo)[i] = make_ushort4(l[0], l[1], l[2], l[3]);
    }
}

// ---------- sort helpers (proven on HW in round 2) ----------
__device__ __forceinline__ void ce(float& a, float& b, bool desc) {
    float lo = fminf(a, b), hi = fmaxf(a, b);
    a = desc ? hi : lo;
    b = desc ? lo : hi;
}

__device__ __forceinline__ void lane_stage(float (&v)[EPT], int tid, int d, int k) {
    const bool keepmax = (((tid & d) == 0) == (((tid * EPT) & k) == 0));
    #pragma unroll
    for (int e = 0; e < EPT; ++e) {
        float w = __shfl_xor(v[e], d, 64);
        v[e] = keepmax ? fmaxf(v[e], w) : fminf(v[e], w);
    }
}

__device__ __forceinline__ void intra_tail(float (&v)[EPT], bool desc) {
    #pragma unroll
    for (int j = 4; j > 0; j >>= 1)
        #pragma unroll
        for (int e = 0; e < EPT; ++e) {
            int f = e ^ j;
            if (f > e) ce(v[e], v[f], desc);
        }
}

// ---------- main kernel: MFMA corr rows + bitonic sort + percentile gather ----------
template<int WS>
__global__ __launch_bounds__(THREADS, 2)
void corr_mfma_sort_kernel(const float* __restrict__ x,
                           const unsigned short* __restrict__ hi,
                           const unsigned short* __restrict__ lo,
                           float* __restrict__ out) {
    __shared__ float rows[4 * M_MAPS];   // 64 KB: one 4-row sort pass

    const int tid  = threadIdx.x;
    const int lane = tid & 63;
    const int w    = tid >> 6;                    // wave 0..7
    const int g    = blockIdx.x;
    // XCD-aware mapping: 2 XCDs per batch so each batch panel stays L2-local
    const int b    = (g & 7) >> 1;                // batch 0..3
    const int gi   = ((g >> 3) << 1) | (g & 1);   // 0..255 within batch
    const int m0   = gi * BM;

    const int lr = lane & 15;                     // A-row / B-col within tile
    const int lg = lane >> 4;                     // k-group 0..3
    const int base = b * (M_MAPS * F_DIM);

    // fetch 8 consecutive bf16 hi/lo values at element offset `off` (batch-rel)
    auto load_hl = [&](int off, bf16x8& oh, bf16x8& ol) {
        if constexpr (WS) {
            oh = *(const bf16x8*)(hi + base + off);
            ol = *(const bf16x8*)(lo + base + off);
        } else {
            const float* p = x + base + off;
            float4 f0 = *(const float4*)(p);
            float4 f1 = *(const float4*)(p + 4);
            float f[8] = {f0.x,f0.y,f0.z,f0.w, f1.x,f1.y,f1.z,f1.w};
            #pragma unroll
            for (int e = 0; e < 8; ++e) {
                unsigned short hbit = f2bf_bits(f[e]);
                oh[e] = (short)hbit;
                ol[e] = (short)f2bf_bits(f[e] - bf_bits2f(hbit));
            }
        }
    };

    // ---- A fragments: block's 16 rows, K=256 (8 chunks), hi+lo ----
    bf16x8 a_hi[8], a_lo[8];
    #pragma unroll
    for (int kk = 0; kk < 8; ++kk)
        load_hl((m0 + lr) * F_DIM + kk * 32 + lg * 8, a_hi[kk], a_lo[kk]);

    // ---- GEMM: 16 x 4096, fully in registers, no LDS, no barriers ----
    f32x4 acc[NT];
    #pragma unroll
    for (int t = 0; t < NT; ++t) acc[t] = (f32x4){0.f, 0.f, 0.f, 0.f};

    #pragma unroll
    for (int t = 0; t < NT; ++t) {
        const int n = t * 128 + w * 16 + lr;      // B col = corr column
        const int rowoff = n * F_DIM + lg * 8;
        #pragma unroll
        for (int kk = 0; kk < 8; ++kk) {
            bf16x8 b_hi, b_lo;
            load_hl(rowoff + kk * 32, b_hi, b_lo);
            acc[t] = __builtin_amdgcn_mfma_f32_16x16x32_bf16(a_hi[kk], b_hi, acc[t], 0, 0, 0);
            acc[t] = __builtin_amdgcn_mfma_f32_16x16x32_bf16(a_lo[kk], b_hi, acc[t], 0, 0, 0);
            acc[t] = __builtin_amdgcn_mfma_f32_16x16x32_bf16(a_hi[kk], b_lo, acc[t], 0, 0, 0);
            acc[t] = __builtin_amdgcn_mfma_f32_16x16x32_bf16(a_lo[kk], b_lo, acc[t], 0, 0, 0);
        }
    }

    // ---- 4 passes: dump 4 rows from accumulators -> sort -> emit ----
    const float scale = 1.0f / F_DIM;
    for (int rg = 0; rg < 4; ++rg) {
        // C/D layout (verified m89/m91): col = lane&15, row = (lane>>4)*4 + reg.
        // Pass rg owns C-rows 4rg..4rg+3 -> lanes with lg==rg hold them.
        // (corr is symmetric, so a row/col transpose here is also harmless.)
        if (lg == rg) {
            #pragma unroll
            for (int t = 0; t < NT; ++t) {
                const int c = t * 128 + w * 16 + lr;
                #pragma unroll
                for (int j = 0; j < 4; ++j)
                    rows[j * M_MAPS + c] = acc[t][j] * scale;
            }
        }
        __syncthreads();

        for (int r = 0; r < 4; ++r) {
            float* R = rows + r * M_MAPS;

            float v[EPT];
            {
                float4 a0 = *(const float4*)&R[tid * EPT];
                float4 a1 = *(const float4*)&R[tid * EPT + 4];
                v[0]=a0.x; v[1]=a0.y; v[2]=a0.z; v[3]=a0.w;
                v[4]=a1.x; v[5]=a1.y; v[6]=a1.z; v[7]=a1.w;
            }

            // k = 2,4,8: intra-thread
            #pragma unroll
            for (int k = 2; k <= EPT; k <<= 1)
                #pragma unroll
                for (int j = k >> 1; j > 0; j >>= 1)
                    #pragma unroll
                    for (int e = 0; e < EPT; ++e) {
                        int f = e ^ j;
                        if (f > e) ce(v[e], v[f], (((tid * EPT + e) & k) == 0));
                    }

            // k = 16..512: wave-internal shuffle stages + intra tail
            #pragma unroll
            for (int k = 16; k <= 512; k <<= 1) {
                #pragma unroll
                for (int j = k >> 1; j >= EPT; j >>= 1)
                    lane_stage(v, tid, j >> 3, k);
                intra_tail(v, ((tid * EPT) & k) == 0);
            }

            // k = 1024..4096: LDS stages for j>=512, then shuffles + tail
            #pragma unroll
            for (int k = 1024; k <= M_MAPS; k <<= 1) {
                *(float4*)&R[tid * EPT]     = make_float4(v[0], v[1], v[2], v[3]);
                *(float4*)&R[tid * EPT + 4] = make_float4(v[4], v[5], v[6], v[7]);
                __syncthreads();
                #pragma unroll
                for (int j = k >> 1; j >= 512; j >>= 1) {
                    const int i0 = tid * 4;
                    const int p  = ((i0 & ~(j - 1)) << 1) | (i0 & (j - 1));
                    const bool desc = ((p & k) == 0);
                    float4 A = *(float4*)&R[p];
                    float4 B = *(float4*)&R[p + j];
                    ce(A.x, B.x, desc); ce(A.y, B.y, desc);
                    ce(A.z, B.z, desc); ce(A.w, B.w, desc);
                    *(float4*)&R[p]     = A;
                    *(float4*)&R[p + j] = B;
                    __syncthreads();
                }
                {
                    float4 a0 = *(const float4*)&R[tid * EPT];
                    float4 a1 = *(const float4*)&R[tid * EPT + 4];
                    v[0]=a0.x; v[1]=a0.y; v[2]=a0.z; v[3]=a0.w;
                    v[4]=a1.x; v[5]=a1.y; v[6]=a1.z; v[7]=a1.w;
                }
                #pragma unroll
                for (int j = 256; j >= EPT; j >>= 1)
                    lane_stage(v, tid, j >> 3, k);
                intra_tail(v, ((tid * EPT) & k) == 0);
            }

            // emit percentile ranks straight from registers (proven formula)
            #pragma unroll
            for (int e = 0; e < EPT; ++e) {
                const int idx = tid * EPT + e;
                const int i = (int)roundf((float)(idx - 1) * (255.0f / 4094.0f));
                if (i >= 0 && i < NPOOL) {
                    const int rk = (int)roundf(1.0f + (float)i * (4094.0f / 255.0f));
                    if (rk == idx)
                        out[((size_t)(b * M_MAPS + m0 + rg * 4 + r)) * NPOOL + i] = v[e];
                }
            }
            __syncthreads();
        }
    }
}

extern "C" void kernel_launch(void* const* d_in, const int* in_sizes, int n_in,
                              void* d_out, int out_size, void* d_ws, size_t ws_size,
                              hipStream_t stream) {
    const float* x = (const float*)d_in[0];
    float* out = (float*)d_out;
    (void)in_sizes; (void)n_in; (void)out_size;

    const size_t nelem = (size_t)NBATCH * M_MAPS * F_DIM;
    const size_t need  = 2 * nelem * sizeof(unsigned short);   // hi + lo
    const int grid = (NBATCH * M_MAPS) / BM;                   // 1024 blocks

    if (ws_size >= need) {
        unsigned short* hi = (unsigned short*)d_ws;
        unsigned short* lo = hi + nelem;
        cvt_split_kernel<<<2048, 256, 0, stream>>>(x, hi, lo);
        corr_mfma_sort_kernel<1><<<grid, THREADS, 0, stream>>>(x, hi, lo, out);
    } else {
        corr_mfma_sort_kernel<0><<<grid, THREADS, 0, stream>>>(x, nullptr, nullptr, out);
    }
}